// Round 7
// baseline (491.018 us; speedup 1.0000x reference)
//
#include <hip/hip_runtime.h>
#include <hip/hip_fp16.h>
#include <math.h>

// Problem constants (fixed by the reference)
constexpr int Nn  = 40000;
constexpr int Ee  = 640000;
constexpr int Fd  = 128;
constexpr int Hid = 256;
constexpr int Cc  = 20;
constexpr float GEN_EPS = 1e-7f;
constexpr float LN_EPS  = 1e-5f;

using bfrag = __attribute__((ext_vector_type(8))) short;   // 8 bf16 (4 VGPR)
using f32x4 = __attribute__((ext_vector_type(4))) float;   // 4 fp32 acc
typedef __attribute__((ext_vector_type(4))) unsigned short us4;

__device__ __forceinline__ unsigned short f2bf(float f) {
  unsigned u = __float_as_uint(f);
  u += 0x7FFF + ((u >> 16) & 1);          // RNE
  return (unsigned short)(u >> 16);
}
__device__ __forceinline__ float bf2f(unsigned short b) {
  return __uint_as_float(((unsigned)b) << 16);
}
__device__ __forceinline__ unsigned packhl(float x) {
  unsigned short hi = f2bf(x);
  unsigned short lo = f2bf(x - bf2f(hi));
  return (unsigned)hi | ((unsigned)lo << 16);
}

// ---------------- CSR build ----------------
__global__ void zero_int_k(int* __restrict__ p, int n) {
  int i = blockIdx.x * 256 + threadIdx.x;
  if (i < n) p[i] = 0;
}

__global__ void count_k(const int* __restrict__ dst, int* __restrict__ cnt) {
  int e = blockIdx.x * 256 + threadIdx.x;
  if (e < Ee) atomicAdd(&cnt[dst[e]], 1);
}

__device__ __forceinline__ int block_incl_scan256(int v) {
  int t = threadIdx.x, lane = t & 63, wid = t >> 6;
  int x = v;
  #pragma unroll
  for (int off = 1; off < 64; off <<= 1) {
    int y = __shfl_up(x, off);
    if (lane >= off) x += y;
  }
  __shared__ int wsum[4];
  if (lane == 63) wsum[wid] = x;
  __syncthreads();
  int add = 0;
  #pragma unroll
  for (int w = 0; w < 4; ++w) if (w < wid) add += wsum[w];
  return x + add;
}

__global__ __launch_bounds__(256) void blocksum_k(const int* __restrict__ cnt,
                                                  int* __restrict__ bsum, int n) {
  int i = blockIdx.x * 256 + threadIdx.x;
  int v = (i < n) ? cnt[i] : 0;
  int lane = threadIdx.x & 63, wid = threadIdx.x >> 6;
  #pragma unroll
  for (int m = 32; m >= 1; m >>= 1) v += __shfl_xor(v, m);
  __shared__ int s4[4];
  if (lane == 0) s4[wid] = v;
  __syncthreads();
  if (threadIdx.x == 0) bsum[blockIdx.x] = s4[0] + s4[1] + s4[2] + s4[3];
}

__global__ __launch_bounds__(256) void scanbsum_k(int* __restrict__ bsum, int nb) {
  int t = threadIdx.x;
  int v = (t < nb) ? bsum[t] : 0;
  int incl = block_incl_scan256(v);
  if (t < nb) bsum[t] = incl - v;   // exclusive
}

__global__ __launch_bounds__(256) void scanfinal_k(const int* __restrict__ cnt,
                                                   const int* __restrict__ bsum,
                                                   int* __restrict__ row_ptr, int n) {
  int b = blockIdx.x, t = threadIdx.x;
  int i = b * 256 + t;
  int v = (i < n) ? cnt[i] : 0;
  int incl = block_incl_scan256(v);
  if (i < n) row_ptr[i + 1] = bsum[b] + incl;
  if (b == 0 && t == 0) row_ptr[0] = 0;
}

// one 8B nontemporal store per edge: {src, edge_weight}
__global__ void scatter_k(const int* __restrict__ src, const int* __restrict__ dst,
                          const float* __restrict__ eattr,
                          const int* __restrict__ row_ptr, int* __restrict__ cur,
                          unsigned long long* __restrict__ cole) {
  int e = blockIdx.x * 256 + threadIdx.x;
  if (e >= Ee) return;
  int d = dst[e];
  int p = row_ptr[d] + atomicAdd(&cur[d], 1);
  unsigned long long v = ((unsigned long long)__float_as_uint(eattr[e]) << 32)
                       | (unsigned)src[e];
  __builtin_nontemporal_store(v, cole + p);
}

// ---------------- weight prep: fp32 -> MFMA-fragment-ordered bf16 hi/lo planes ----------------
// out idx = layer*32768 + (tk*64 + l)*8 + j, tk = kc*16+tt (w1) / kc*8+tt (w2)
// k = kc*32 + (l>>4)*4 + (j&3) + 16*(j>>2);  c = tt*16 + (l&15)
__global__ void prep_w_k(const float* __restrict__ w1, const float* __restrict__ w2,
                         unsigned short* __restrict__ w1h, unsigned short* __restrict__ w1l,
                         unsigned short* __restrict__ w2h, unsigned short* __restrict__ w2l) {
  int i = blockIdx.x * 256 + threadIdx.x;
  constexpr int TOT = 3 * Fd * Hid;   // 98304
  if (i >= TOT) return;
  int j = i & 7, l = (i >> 3) & 63, tk = (i >> 9) & 63, layer = i >> 15;
  int k_lo = (l >> 4) * 4 + (j & 3) + 16 * (j >> 2);
  {
    int kc = tk >> 4, tt = tk & 15;          // w1: K=128 (kc<4), N=256 (tt<16)
    int k = kc * 32 + k_lo, c = tt * 16 + (l & 15);
    float v = w1[((size_t)layer * Fd + k) * Hid + c];
    unsigned short hi = f2bf(v);
    w1h[i] = hi; w1l[i] = f2bf(v - bf2f(hi));
  }
  {
    int kc = tk >> 3, tt = tk & 7;           // w2: K=256 (kc<8), N=128 (tt<8)
    int k = kc * 32 + k_lo, c = tt * 16 + (l & 15);
    float v = w2[((size_t)layer * Hid + k) * Fd + c];
    unsigned short hi = f2bf(v);
    w2h[i] = hi; w2l[i] = f2bf(v - bf2f(hi));
  }
}

// ---------------- fused embedding gather + layer-0 LN/ReLU + deg/dis ----------------
__global__ __launch_bounds__(256) void embed_ln_k(const int* __restrict__ ids,
                                                  const float* __restrict__ emb,
                                                  const float* __restrict__ g,
                                                  const float* __restrict__ b,
                                                  const int* __restrict__ row_ptr,
                                                  const uint2* __restrict__ cole,
                                                  float* __restrict__ h,
                                                  float* __restrict__ xn,
                                                  __half* __restrict__ xnh,
                                                  float* __restrict__ dis) {
  int node = blockIdx.x * 4 + (threadIdx.x >> 6);
  int lane = threadIdx.x & 63;
  float2 v = *(const float2*)(emb + (size_t)ids[node] * Fd + lane * 2);
  *(float2*)(h + (size_t)node * Fd + lane * 2) = v;
  float s = v.x + v.y;
  #pragma unroll
  for (int m = 32; m >= 1; m >>= 1) s += __shfl_xor(s, m);
  float mu = s * (1.f / 128.f);
  float d0 = v.x - mu, d1 = v.y - mu;
  float q = d0 * d0 + d1 * d1;
  #pragma unroll
  for (int m = 32; m >= 1; m >>= 1) q += __shfl_xor(q, m);
  float rs = rsqrtf(q * (1.f / 128.f) + LN_EPS);
  float2 gg = *(const float2*)(g + lane * 2);
  float2 bb = *(const float2*)(b + lane * 2);
  float ox = fmaxf(d0 * rs * gg.x + bb.x, 0.f);
  float oy = fmaxf(d1 * rs * gg.y + bb.y, 0.f);
  *(float2*)(xn + (size_t)node * Fd + lane * 2) = make_float2(ox, oy);
  *(__half2*)(xnh + (size_t)node * Fd + lane * 2) = __floats2half2_rn(ox, oy);
  if (lane == 0) {           // GCN degree (incl self loop) -> dis = rsqrt(deg)
    int be = row_ptr[node], en = row_ptr[node + 1];
    float sd = 1.f;
    for (int j = be; j < en; ++j) sd += __uint_as_float(cole[j].y);
    dis[node] = (sd > 0.f) ? rsqrtf(sd) : 0.f;
  }
}

// ---------------- GENConv aggregation (single pass; fp16 gathers; 16-deep batch) ----------------
__global__ __launch_bounds__(256) void gen_agg_k(const float* __restrict__ xn,
                                                 const __half2* __restrict__ xnh,
                                                 const int* __restrict__ row_ptr,
                                                 const uint2* __restrict__ cole,
                                                 const float* __restrict__ t_ptr,
                                                 unsigned* __restrict__ h2p) {
  int node = blockIdx.x * 4 + (threadIdx.x >> 6);
  int lane = threadIdx.x & 63;
  float t = t_ptr[0];
  int beg = row_ptr[node], end = row_ptr[node + 1];
  const __half2* xl = xnh + lane;           // row stride 64 half2
  float sex = 0.f, sey = 0.f, smx = 0.f, smy = 0.f;

  int j = beg;
  for (; j + 16 <= end; j += 16) {
    int cs[16];
    #pragma unroll
    for (int k = 0; k < 16; ++k) cs[k] = (int)cole[j + k].x;
    __half2 hv[16];
    #pragma unroll
    for (int k = 0; k < 16; ++k) hv[k] = xl[(size_t)cs[k] * 64];
    #pragma unroll
    for (int k = 0; k < 16; ++k) {
      float2 v = __half22float2(hv[k]);
      float mgx = v.x + GEN_EPS;
      float mgy = v.y + GEN_EPS;
      float ex = __expf(t * mgx);
      float ey = __expf(t * mgy);
      sex += ex;  sey += ey;
      smx = fmaf(mgx, ex, smx);
      smy = fmaf(mgy, ey, smy);
    }
  }
  for (; j < end; ++j) {
    float2 v = __half22float2(xl[(size_t)cole[j].x * 64]);
    float mgx = v.x + GEN_EPS;
    float mgy = v.y + GEN_EPS;
    float ex = __expf(t * mgx);
    float ey = __expf(t * mgy);
    sex += ex;  sey += ey;
    smx = fmaf(mgx, ex, smx);
    smy = fmaf(mgy, ey, smy);
  }

  float2 self = *(const float2*)(xn + (size_t)node * Fd + lane * 2);
  float ox = self.x + smx / (sex + 1e-16f);
  float oy = self.y + smy / (sey + 1e-16f);
  uint2 o;
  o.x = packhl(ox);
  o.y = packhl(oy);
  *(uint2*)(h2p + (size_t)node * Fd + lane * 2) = o;
}

// ---- shared A-staging helper: stage 128 K-cols of 64 rows, fragment-permuted ----
// thread t: row = t>>2, k-base = (t&3)*32; 8 uint4 loads -> 16 us4 LDS stores
__device__ __forceinline__ void stage_A128(const unsigned* __restrict__ Ap,
                                           int r0, int rowStride, int kOff,
                                           unsigned short (*Ah)[136],
                                           unsigned short (*Al)[136]) {
  int t = threadIdx.x;
  int row = t >> 2;
  int base = (t & 3) * 32;
  const unsigned* sp = Ap + (size_t)(r0 + row) * rowStride + kOff + base;
  #pragma unroll
  for (int hb = 0; hb < 8; ++hb) {
    int kk0 = hb * 4;
    uint4 a = *(const uint4*)(sp + kk0);
    int d = base + 8 * ((kk0 & 15) >> 2) + 4 * (kk0 >> 4);
    us4 hi = {(unsigned short)a.x, (unsigned short)a.y,
              (unsigned short)a.z, (unsigned short)a.w};
    us4 lo = {(unsigned short)(a.x >> 16), (unsigned short)(a.y >> 16),
              (unsigned short)(a.z >> 16), (unsigned short)(a.w >> 16)};
    *(us4*)&Ah[row][d] = hi;
    *(us4*)&Al[row][d] = lo;
  }
}

// ---------------- GEMM1 (MFMA bf16-split, 1 barrier, B frags from global) + LN + ReLU ----------------
__global__ __launch_bounds__(256) void gemm1m_k(const unsigned* __restrict__ Ap,
                                                const unsigned short* __restrict__ Bhp,
                                                const unsigned short* __restrict__ Blp,
                                                const float* __restrict__ bias,
                                                const float* __restrict__ gam,
                                                const float* __restrict__ bln,
                                                unsigned* __restrict__ Zp) {
  __shared__ unsigned short Ah[64][136], Al[64][136];
  const int t = threadIdx.x;
  const int w = t >> 6, l = t & 63;
  const int g4 = l >> 4, cl = l & 15;
  const int r0 = blockIdx.x * 64;
  f32x4 acc[16];
  #pragma unroll
  for (int i = 0; i < 16; ++i) acc[i] = (f32x4){0.f, 0.f, 0.f, 0.f};

  stage_A128(Ap, r0, Fd, 0, Ah, Al);
  __syncthreads();

  for (int kc = 0; kc < 4; ++kc) {
    bfrag ah = *(const bfrag*)&Ah[16 * w + cl][kc * 32 + g4 * 8];
    bfrag al = *(const bfrag*)&Al[16 * w + cl][kc * 32 + g4 * 8];
    const unsigned short* bh = Bhp + ((size_t)(kc * 16) * 64 + l) * 8;
    const unsigned short* bl = Blp + ((size_t)(kc * 16) * 64 + l) * 8;
    #pragma unroll
    for (int tt = 0; tt < 16; ++tt) {
      bfrag vbh = *(const bfrag*)(bh + tt * 512);
      bfrag vbl = *(const bfrag*)(bl + tt * 512);
      acc[tt] = __builtin_amdgcn_mfma_f32_16x16x32_bf16(ah, vbh, acc[tt], 0, 0, 0);
      acc[tt] = __builtin_amdgcn_mfma_f32_16x16x32_bf16(ah, vbl, acc[tt], 0, 0, 0);
      acc[tt] = __builtin_amdgcn_mfma_f32_16x16x32_bf16(al, vbh, acc[tt], 0, 0, 0);
    }
  }

  // epilogue: +bias, LN over 256 cols (16 lanes x 16 tiles), relu, pack
  float bcol[16], gcol[16], blc[16];
  #pragma unroll
  for (int tt = 0; tt < 16; ++tt) {
    int c = 16 * tt + cl;
    bcol[tt] = bias[c]; gcol[tt] = gam[c]; blc[tt] = bln[c];
  }
  #pragma unroll
  for (int j = 0; j < 4; ++j) {
    float x[16];
    float s = 0.f, q = 0.f;
    #pragma unroll
    for (int tt = 0; tt < 16; ++tt) {
      x[tt] = acc[tt][j] + bcol[tt];
      s += x[tt];
      q = fmaf(x[tt], x[tt], q);
    }
    #pragma unroll
    for (int m = 8; m >= 1; m >>= 1) { s += __shfl_xor(s, m); q += __shfl_xor(q, m); }
    float mu = s * (1.f / 256.f);
    float rs = rsqrtf(q * (1.f / 256.f) - mu * mu + LN_EPS);
    int row = r0 + 16 * w + 4 * g4 + j;
    #pragma unroll
    for (int tt = 0; tt < 16; ++tt) {
      float z = fmaxf((x[tt] - mu) * rs * gcol[tt] + blc[tt], 0.f);
      Zp[(size_t)row * Hid + 16 * tt + cl] = packhl(z);
    }
  }
}

// ---------------- GEMM2 (MFMA bf16-split, 3 barriers) + residual + {LN/ReLU | xwd} ----------------
// mode 0: H += ..., XN/XNh = relu(LN(H));  mode 2: xwdh = fp16(dis * (H_new @ gw)), H not stored
__global__ __launch_bounds__(256) void gemm2m_k(const unsigned* __restrict__ Ap,
                                                const unsigned short* __restrict__ Bhp,
                                                const unsigned short* __restrict__ Blp,
                                                const float* __restrict__ bias,
                                                float* __restrict__ H,
                                                const float* __restrict__ gam,
                                                const float* __restrict__ bln,
                                                float* __restrict__ XN,
                                                __half* __restrict__ XNh,
                                                const float* __restrict__ gw,
                                                const float* __restrict__ dis,
                                                __half* __restrict__ xwdh,
                                                int mode) {
  __shared__ unsigned short Ah[64][136], Al[64][136];
  __shared__ float gwS[Fd * Cc];
  const int t = threadIdx.x;
  const int w = t >> 6, l = t & 63;
  const int g4 = l >> 4, cl = l & 15;
  const int r0 = blockIdx.x * 64;
  f32x4 acc[8];
  #pragma unroll
  for (int i = 0; i < 8; ++i) acc[i] = (f32x4){0.f, 0.f, 0.f, 0.f};

  if (mode == 2) {
    for (int i = t; i < Fd * Cc; i += 256) gwS[i] = gw[i];
  }

  for (int half = 0; half < 2; ++half) {
    if (half) __syncthreads();            // protect LDS reuse
    stage_A128(Ap, r0, Hid, half * 128, Ah, Al);
    __syncthreads();
    for (int kc = 0; kc < 4; ++kc) {
      int kf = half * 4 + kc;
      bfrag ah = *(const bfrag*)&Ah[16 * w + cl][kc * 32 + g4 * 8];
      bfrag al = *(const bfrag*)&Al[16 * w + cl][kc * 32 + g4 * 8];
      const unsigned short* bh = Bhp + ((size_t)(kf * 8) * 64 + l) * 8;
      const unsigned short* bl = Blp + ((size_t)(kf * 8) * 64 + l) * 8;
      #pragma unroll
      for (int tt = 0; tt < 8; ++tt) {
        bfrag vbh = *(const bfrag*)(bh + tt * 512);
        bfrag vbl = *(const bfrag*)(bl + tt * 512);
        acc[tt] = __builtin_amdgcn_mfma_f32_16x16x32_bf16(ah, vbh, acc[tt], 0, 0, 0);
        acc[tt] = __builtin_amdgcn_mfma_f32_16x16x32_bf16(ah, vbl, acc[tt], 0, 0, 0);
        acc[tt] = __builtin_amdgcn_mfma_f32_16x16x32_bf16(al, vbh, acc[tt], 0, 0, 0);
      }
    }
  }

  float bcol[8], gcol[8], blc[8];
  #pragma unroll
  for (int tt = 0; tt < 8; ++tt) {
    int c = 16 * tt + cl;
    bcol[tt] = bias[c];
    if (mode == 0) { gcol[tt] = gam[c]; blc[tt] = bln[c]; }
  }
  #pragma unroll
  for (int j = 0; j < 4; ++j) {
    int row = r0 + 16 * w + 4 * g4 + j;
    float x[8];
    float s = 0.f, q = 0.f;
    #pragma unroll
    for (int tt = 0; tt < 8; ++tt) {
      size_t off = (size_t)row * Fd + 16 * tt + cl;
      float hv = H[off] + acc[tt][j] + bcol[tt];
      x[tt] = hv;
      if (mode == 0) {
        H[off] = hv;
        s += hv;
        q = fmaf(hv, hv, q);
      }
    }
    if (mode == 0) {
      #pragma unroll
      for (int m = 8; m >= 1; m >>= 1) { s += __shfl_xor(s, m); q += __shfl_xor(q, m); }
      float mu = s * (1.f / 128.f);
      float rs = rsqrtf(q * (1.f / 128.f) - mu * mu + LN_EPS);
      #pragma unroll
      for (int tt = 0; tt < 8; ++tt) {
        float z = fmaxf((x[tt] - mu) * rs * gcol[tt] + blc[tt], 0.f);
        size_t off = (size_t)row * Fd + 16 * tt + cl;
        XN[off] = z;
        XNh[off] = __float2half_rn(z);
      }
    } else {
      // xwd: p[c] = sum_col H[row][col]*gw[col][c]; reduce over 16 lanes; *dis; fp16
      float p[Cc];
      #pragma unroll
      for (int c = 0; c < Cc; ++c) p[c] = 0.f;
      #pragma unroll
      for (int tt = 0; tt < 8; ++tt) {
        const float* wr = &gwS[(16 * tt + cl) * Cc];
        float xv = x[tt];
        #pragma unroll
        for (int c = 0; c < Cc; ++c) p[c] = fmaf(xv, wr[c], p[c]);
      }
      #pragma unroll
      for (int m = 8; m >= 1; m >>= 1)
        #pragma unroll
        for (int c = 0; c < Cc; ++c) p[c] += __shfl_xor(p[c], m);
      float v = p[0];
      #pragma unroll
      for (int c = 1; c < Cc; ++c) if (cl == c) v = p[c];
      float v2 = p[16];
      #pragma unroll
      for (int c = 17; c < Cc; ++c) if (cl == c - 16) v2 = p[c];
      float dvr = dis[row];
      xwdh[(size_t)row * 32 + cl] = __float2half_rn(v * dvr);
      if (cl < 4) xwdh[(size_t)row * 32 + 16 + cl] = __float2half_rn(v2 * dvr);
    }
  }
}

// ---------------- GCN output: edge gather (1 line/edge) + self + bias + log_softmax ----------------
__global__ __launch_bounds__(256) void gcn_out_k(const __half* __restrict__ xwdh,
                                                 const int* __restrict__ row_ptr,
                                                 const uint2* __restrict__ cole,
                                                 const float* __restrict__ dis,
                                                 const float* __restrict__ bias,
                                                 float* __restrict__ out) {
  int node = blockIdx.x * 4 + (threadIdx.x >> 6);
  int lane = threadIdx.x & 63;
  int grp = lane / Cc, c = lane % Cc;       // grp 0..2 active, 3 = idle tail lanes
  float dv = dis[node];
  float acc = 0.f;
  int beg = row_ptr[node], end = row_ptr[node + 1];
  if (grp < 3) {
    for (int j = beg + grp; j < end; j += 3) {
      uint2 ce = cole[j];
      acc += __uint_as_float(ce.y) * __half2float(xwdh[(size_t)ce.x * 32 + c]);
    }
  }
  int l20 = lane + 20 < 64 ? lane + 20 : lane;
  int l40 = lane + 40 < 64 ? lane + 40 : lane;
  float tot = acc + __shfl(acc, l20) + __shfl(acc, l40);
  float val = 0.f;
  if (lane < Cc)
    val = dv * tot + dv * __half2float(xwdh[(size_t)node * 32 + c]) + bias[c];
  float red = (lane < Cc) ? val : -INFINITY;
  #pragma unroll
  for (int m = 32; m >= 1; m >>= 1) red = fmaxf(red, __shfl_xor(red, m));
  float ex = (lane < Cc) ? __expf(val - red) : 0.f;
  #pragma unroll
  for (int m = 32; m >= 1; m >>= 1) ex += __shfl_xor(ex, m);
  float ls = __logf(ex);
  if (lane < Cc) out[(size_t)node * Cc + c] = val - red - ls;
}

// ---------------- host ----------------
extern "C" void kernel_launch(void* const* d_in, const int* in_sizes, int n_in,
                              void* d_out, int out_size, void* d_ws, size_t ws_size,
                              hipStream_t stream) {
  const int*   x_ids = (const int*)d_in[0];
  const int*   ei    = (const int*)d_in[1];
  const int*   srcp  = ei;
  const int*   dstp  = ei + Ee;
  const float* eattr = (const float*)d_in[2];
  const float* emb   = (const float*)d_in[3];
  const float* ln_g  = (const float*)d_in[4];
  const float* ln_b  = (const float*)d_in[5];
  const float* tpar  = (const float*)d_in[6];
  const float* w1    = (const float*)d_in[7];
  const float* b1    = (const float*)d_in[8];
  const float* mg    = (const float*)d_in[9];
  const float* mb    = (const float*)d_in[10];
  const float* w2    = (const float*)d_in[11];
  const float* b2    = (const float*)d_in[12];
  const float* gw    = (const float*)d_in[13];
  const float* gb    = (const float*)d_in[14];
  float* out = (float*)d_out;

  char* ws = (char*)d_ws;
  float* h   = (float*)ws;  ws += (size_t)Nn * Fd * 4;
  float* xn  = (float*)ws;  ws += (size_t)Nn * Fd * 4;
  __half* xnh = (__half*)ws; ws += (size_t)Nn * Fd * 2;
  __half* xwdh = (__half*)ws; ws += (size_t)Nn * 32 * 2;
  float* dis = (float*)ws;  ws += (size_t)Nn * 4;
  unsigned* h2p = (unsigned*)ws; ws += (size_t)Nn * Fd * 4;
  unsigned* z1p = (unsigned*)ws; ws += (size_t)Nn * Hid * 4;
  unsigned short* w1h = (unsigned short*)ws; ws += (size_t)3 * Fd * Hid * 2;
  unsigned short* w1l = (unsigned short*)ws; ws += (size_t)3 * Fd * Hid * 2;
  unsigned short* w2h = (unsigned short*)ws; ws += (size_t)3 * Fd * Hid * 2;
  unsigned short* w2l = (unsigned short*)ws; ws += (size_t)3 * Fd * Hid * 2;
  int* row_ptr = (int*)ws; ws += (size_t)(Nn + 16) * 4;
  int* cnt  = (int*)ws;    ws += (size_t)2 * Nn * 4;   // [0,N)=counts, [N,2N)=cursors
  unsigned long long* cole = (unsigned long long*)ws; ws += (size_t)Ee * 8;
  int* bsum = (int*)ws;    ws += 256 * 4;
  if ((size_t)(ws - (char*)d_ws) > ws_size) return;  // workspace too small

  constexpr int NB = (Nn + 255) / 256;  // 157

  prep_w_k<<<(3 * Fd * Hid + 255) / 256, 256, 0, stream>>>(w1, w2, w1h, w1l, w2h, w2l);

  // CSR by destination (rebuilt every call; deterministic work)
  zero_int_k<<<2 * NB, 256, 0, stream>>>(cnt, 2 * Nn);
  count_k<<<2500, 256, 0, stream>>>(dstp, cnt);
  blocksum_k<<<NB, 256, 0, stream>>>(cnt, bsum, Nn);
  scanbsum_k<<<1, 256, 0, stream>>>(bsum, NB);
  scanfinal_k<<<NB, 256, 0, stream>>>(cnt, bsum, row_ptr, Nn);
  scatter_k<<<2500, 256, 0, stream>>>(srcp, dstp, eattr, row_ptr, cnt + Nn, cole);

  embed_ln_k<<<Nn / 4, 256, 0, stream>>>(x_ids, emb, ln_g, ln_b, row_ptr,
                                         (const uint2*)cole, h, xn, xnh, dis);

  for (int i = 0; i < 3; ++i) {
    gen_agg_k<<<Nn / 4, 256, 0, stream>>>(xn, (const __half2*)xnh, row_ptr,
                                          (const uint2*)cole, tpar + i, h2p);
    gemm1m_k<<<Nn / 64, 256, 0, stream>>>(h2p,
        w1h + (size_t)i * Fd * Hid, w1l + (size_t)i * Fd * Hid,
        b1 + i * Hid, mg + i * Hid, mb + i * Hid, z1p);
    gemm2m_k<<<Nn / 64, 256, 0, stream>>>(z1p,
        w2h + (size_t)i * Fd * Hid, w2l + (size_t)i * Fd * Hid,
        b2 + i * Fd, h,
        ln_g + (i + 1) * Fd, ln_b + (i + 1) * Fd,
        xn, xnh, gw, dis, xwdh, (i < 2) ? 0 : 2);
  }

  gcn_out_k<<<Nn / 4, 256, 0, stream>>>(xwdh, row_ptr, (const uint2*)cole, dis, gb, out);
}